// Round 1
// baseline (158.189 us; speedup 1.0000x reference)
//
#include <hip/hip_runtime.h>

// B=16, C=256, HEADS=4, d=64, N=W*H=1024
constexpr int Bb  = 16;
constexpr int Cch = 256;
constexpr int NH  = 4;
constexpr int Dh  = 64;
constexpr int Nn  = 1024;

typedef _Float16 f16;
typedef __attribute__((ext_vector_type(8))) _Float16 f16x8;
typedef __attribute__((ext_vector_type(4))) _Float16 f16x4;
typedef __attribute__((ext_vector_type(4))) float    f32x4;

// ---------------------------------------------------------------------------
// Fused prep: xtrans (blocks 0..1023) | relt (1024..2047) | wcast (2048..2815)
// ---------------------------------------------------------------------------
__global__ __launch_bounds__(256) void prep_kernel(
    const float* __restrict__ x,
    const float* __restrict__ Wq, const float* __restrict__ Wk,
    const float* __restrict__ Wv,
    const float* __restrict__ rel_h, const float* __restrict__ rel_w,
    f16* __restrict__ xt, f16* __restrict__ Wh, f16* __restrict__ rel_t)
{
    const int gx = blockIdx.x;
    const int t  = threadIdx.x;
    __shared__ float T[64][65];

    if (gx < 1024) {
        // xt[b][n][c] = f16(x[b][c][n]), 64x64 LDS transpose tiles
        const int n0 = (gx & 15) * 64;
        const int c0 = ((gx >> 4) & 3) * 64;
        const int b  = gx >> 6;
        #pragma unroll
        for (int rep = 0; rep < 16; rep++) {
            const int e  = t + rep * 256;
            const int r  = e >> 6;    // c
            const int cc = e & 63;    // n
            T[r][cc] = x[((size_t)b * Cch + c0 + r) * Nn + n0 + cc];
        }
        __syncthreads();
        #pragma unroll
        for (int rep = 0; rep < 4; rep++) {
            const int e  = t + rep * 256;
            const int nn = e >> 4;
            const int c4 = e & 15;
            f16x4 w;
            w.x = (f16)T[c4 * 4 + 0][nn];
            w.y = (f16)T[c4 * 4 + 1][nn];
            w.z = (f16)T[c4 * 4 + 2][nn];
            w.w = (f16)T[c4 * 4 + 3][nn];
            *(f16x4*)&xt[((size_t)b * Nn + n0 + nn) * Cch + c0 + c4 * 4] = w;
        }
    } else if (gx < 2048) {
        // rel_t[h][n][d] = f16(rel_h[h][d][n&31] + rel_w[h][d][n>>5])
        const int idx = (gx - 1024) * 256 + t;     // NH*Nn*Dh = 262144
        const int d = idx & 63;
        const int n = (idx >> 6) & (Nn - 1);
        const int h = idx >> 16;
        const int hd = h * 64 + d;
        rel_t[idx] = (f16)(rel_h[hd * 32 + (n & 31)] + rel_w[hd * 32 + (n >> 5)]);
    } else {
        // Wh[p*256+o][c] = f16(W[o][c])
        const int idx = (gx - 2048) * 256 + t;     // 768*256 = 196608
        const int og  = idx >> 8;
        const int c   = idx & 255;
        const int p   = og >> 8;
        const int o   = og & 255;
        const float* W = (p == 0) ? Wq : (p == 1) ? Wk : Wv;
        Wh[idx] = (f16)W[o * 256 + c];
    }
}

// ---------------------------------------------------------------------------
// QKV projection GEMM, fp16 MFMA (unchanged; ST=40 is conflict-free).
// ---------------------------------------------------------------------------
__global__ __launch_bounds__(256) void gemm_qkv(
    const f16* __restrict__ Wh, const f16* __restrict__ xt,
    const float* __restrict__ bq, const float* __restrict__ bk,
    const float* __restrict__ bv,
    f16* __restrict__ qt, f16* __restrict__ kt, f16* __restrict__ vb)
{
    const int bx   = blockIdx.x;
    const int y    = blockIdx.y;
    const int b    = blockIdx.z;
    const int p    = y >> 1;
    const int half = y & 1;

    constexpr int ST = 40;
    __shared__ f16 Wt[128 * ST];
    __shared__ f16 Xt[128 * ST];

    const int t    = threadIdx.x;
    const int wave = t >> 6;
    const int lane = t & 63;
    const int l16  = lane & 15;
    const int quad = lane >> 4;
    const int wm   = wave >> 1;
    const int wsd  = wave & 1;

    f32x4 acc[4][4];
    #pragma unroll
    for (int mi = 0; mi < 4; mi++)
        #pragma unroll
        for (int ni = 0; ni < 4; ni++) acc[mi][ni] = (f32x4){0.f, 0.f, 0.f, 0.f};

    const f16* Wg = Wh + (size_t)y * 128 * 256;
    const f16* Xg = xt + ((size_t)b * Nn + bx * 128) * 256;

    for (int c0 = 0; c0 < 256; c0 += 32) {
        f16x8 wch[2], xch[2];
        #pragma unroll
        for (int rep = 0; rep < 2; rep++) {
            const int e   = t + rep * 256;
            const int row = e >> 2;
            const int c8  = e & 3;
            wch[rep] = *(const f16x8*)&Wg[(size_t)row * 256 + c0 + c8 * 8];
            xch[rep] = *(const f16x8*)&Xg[(size_t)row * 256 + c0 + c8 * 8];
        }
        __syncthreads();
        #pragma unroll
        for (int rep = 0; rep < 2; rep++) {
            const int e   = t + rep * 256;
            const int row = e >> 2;
            const int c8  = e & 3;
            *(f16x8*)&Wt[row * ST + c8 * 8] = wch[rep];
            *(f16x8*)&Xt[row * ST + c8 * 8] = xch[rep];
        }
        __syncthreads();

        const f16* tf = (p < 2) ? Wt : Xt;
        const f16* ts = (p < 2) ? Xt : Wt;
        f16x8 af[4], bf[4];
        #pragma unroll
        for (int mi = 0; mi < 4; mi++)
            af[mi] = *(const f16x8*)&tf[(wm * 64 + mi * 16 + l16) * ST + quad * 8];
        #pragma unroll
        for (int ni = 0; ni < 4; ni++)
            bf[ni] = *(const f16x8*)&ts[(wsd * 64 + ni * 16 + l16) * ST + quad * 8];
        #pragma unroll
        for (int mi = 0; mi < 4; mi++)
            #pragma unroll
            for (int ni = 0; ni < 4; ni++)
                acc[mi][ni] = __builtin_amdgcn_mfma_f32_16x16x32_f16(
                    af[mi], bf[ni], acc[mi][ni], 0, 0, 0);
    }

    if (p < 2) {
        f16* yt = (p == 0) ? qt : kt;
        const float* bg = (p == 0) ? bq : bk;
        #pragma unroll
        for (int mi = 0; mi < 4; mi++) {
            const int o_in = half * 128 + wm * 64 + mi * 16 + quad * 4;
            const float4 b4 = *(const float4*)&bg[o_in];
            const int h = o_in >> 6;
            const int d = o_in & 63;
            #pragma unroll
            for (int ni = 0; ni < 4; ni++) {
                const int n = bx * 128 + wsd * 64 + ni * 16 + l16;
                f16x4 w;
                w.x = (f16)(acc[mi][ni][0] + b4.x);
                w.y = (f16)(acc[mi][ni][1] + b4.y);
                w.z = (f16)(acc[mi][ni][2] + b4.z);
                w.w = (f16)(acc[mi][ni][3] + b4.w);
                *(f16x4*)&yt[(((size_t)b * NH + h) * Nn + n) * Dh + d] = w;
            }
        }
    } else {
        #pragma unroll
        for (int ni = 0; ni < 4; ni++) {
            const int c  = half * 128 + wsd * 64 + ni * 16 + l16;
            const float bs = bv[c];
            #pragma unroll
            for (int mi = 0; mi < 4; mi++) {
                const int n = bx * 128 + wm * 64 + mi * 16 + quad * 4;
                f16x4 w;
                w.x = (f16)(acc[mi][ni][0] + bs);
                w.y = (f16)(acc[mi][ni][1] + bs);
                w.z = (f16)(acc[mi][ni][2] + bs);
                w.w = (f16)(acc[mi][ni][3] + bs);
                *(f16x4*)&vb[((size_t)b * Cch + c) * Nn + n] = w;
            }
        }
    }
}

// ---------------------------------------------------------------------------
// Flash attention, fp16 MFMA, XOR-swizzled LDS.
// ROUND 1 change: software-pipelined K/V staging (T14/T3 pattern).
//  - Double-buffered Ka/v in LDS; global loads for tile j+2 issued at the END
//    of iteration j, LDS write of tile j+1 at the end of iteration j's compute
//    -> HBM/L2 latency hidden under a full compute phase; vmcnt drain is free.
//  - ONE barrier per iteration (was 2): 18 barriers/block vs 33.
//  - Qa (32 KB) is dead after the A-frag hoist -> aliased over the two Ka
//    buffers. LDS total 64 KB; occupancy unchanged (grid-limited 2 blocks/CU).
// grid = (N/128, NH, B), block = 256.
// ---------------------------------------------------------------------------
__global__ __launch_bounds__(256, 2) void attn_mfma(
    const f16* __restrict__ qt, const f16* __restrict__ kt,
    const f16* __restrict__ relt, const f16* __restrict__ vb,
    float* __restrict__ out)
{
    const int i0 = blockIdx.x * 128;
    const int h  = blockIdx.y;
    const int b  = blockIdx.z;
    const int bh = b * NH + h;

    const f16* qtb = qt  + (size_t)bh * Nn * Dh;            // [n][64]
    const f16* ktb = kt  + (size_t)bh * Nn * Dh;            // [n][64]
    const f16* rlt = relt + (size_t)h * Nn * Dh;            // [n][64]
    const f16* vbb = vb  + (size_t)(b * Cch + h * Dh) * Nn; // [d][1024]

    // XOR-swizzled tiles: elem(row, col) at row*W + ((col>>3 ^ (row&7))<<3) + (col&7)
    // 64 KB pool: Ka0|Ka1 (2x 8192 f16), Vs0|Vs1 (2x 4096), Pt (8192).
    // Qa (16384 f16) aliases Ka0|Ka1 during the prologue only.
    __shared__ __align__(16) f16 smem[32768];
    f16* const Ka0  = smem;
    f16* const Ka1  = smem + 8192;
    f16* const Vs0  = smem + 16384;
    f16* const Vs1  = smem + 20480;
    f16* const Pt_s = smem + 24576;
    f16* const Qa_s = smem;          // alias (prologue only)

    const int t    = threadIdx.x;
    const int wave = t >> 6;
    const int lane = t & 63;
    const int l16  = lane & 15;
    const int quad = lane >> 4;

    // ---- stage Qa = [q | rel]: 128 rows x 128 f16, swizzled ----
    #pragma unroll
    for (int rep = 0; rep < 8; rep++) {
        const int e   = t + rep * 256;
        const int row = e >> 4;
        const int c8  = e & 15;
        const f16* src = (c8 < 8)
            ? &qtb[(size_t)(i0 + row) * Dh + c8 * 8]
            : &rlt[(size_t)(i0 + row) * Dh + (c8 - 8) * 8];
        *(f16x8*)&Qa_s[(row << 7) + ((c8 ^ (row & 7)) << 3)] = *(const f16x8*)src;
    }
    __syncthreads();

    // ---- hoist Qa A-fragments (j-invariant): 2 m-subtiles x 4 k-slices ----
    f16x8 af[2][4];
    #pragma unroll
    for (int ms = 0; ms < 2; ms++) {
        const int row = wave * 32 + ms * 16 + l16;
        #pragma unroll
        for (int k = 0; k < 4; k++)
            af[ms][k] = *(const f16x8*)
                &Qa_s[(row << 7) + ((((k << 2) + quad) ^ (row & 7)) << 3)];
    }

    f16x8 ones;
    #pragma unroll
    for (int u = 0; u < 8; u++) ones[u] = (f16)1.0f;

    f32x4 Of[2][4], Ol[2];
    float m_r[2][4];
    #pragma unroll
    for (int ms = 0; ms < 2; ms++) {
        Ol[ms] = (f32x4){0.f, 0.f, 0.f, 0.f};
        #pragma unroll
        for (int ds = 0; ds < 4; ds++) Of[ms][ds] = (f32x4){0.f, 0.f, 0.f, 0.f};
        #pragma unroll
        for (int r = 0; r < 4; r++) m_r[ms][r] = -1e30f;
    }

    f16x8 kreg[4], vreg[2];

    auto load_kv = [&](int j0) {
        #pragma unroll
        for (int rep = 0; rep < 4; rep++) {
            const int e   = t + rep * 256;
            const int row = e >> 4;
            const int c8  = e & 15;
            const f16* src = (c8 < 8)
                ? &ktb[(size_t)(j0 + row) * Dh + c8 * 8]
                : &qtb[(size_t)(j0 + row) * Dh + (c8 - 8) * 8];
            kreg[rep] = *(const f16x8*)src;
        }
        #pragma unroll
        for (int rep = 0; rep < 2; rep++) {
            const int e   = t + rep * 256;
            const int row = e >> 3;
            const int c8  = e & 7;
            vreg[rep] = *(const f16x8*)&vbb[(size_t)row * Nn + j0 + c8 * 8];
        }
    };

    auto store_kv = [&](f16* Kb, f16* Vb) {
        #pragma unroll
        for (int rep = 0; rep < 4; rep++) {
            const int e   = t + rep * 256;
            const int row = e >> 4;
            const int c8  = e & 15;
            *(f16x8*)&Kb[(row << 7) + ((c8 ^ (row & 7)) << 3)] = kreg[rep];
        }
        #pragma unroll
        for (int rep = 0; rep < 2; rep++) {
            const int e   = t + rep * 256;
            const int row = e >> 3;
            const int c8  = e & 7;
            *(f16x8*)&Vb[(row << 6) + ((c8 ^ (row & 7)) << 3)] = vreg[rep];
        }
    };

    // ---- pipeline prologue ----
    load_kv(0);
    __syncthreads();              // all waves done reading aliased Qa
    store_kv(Ka0, Vs0);           // tile 0 -> buf 0
    load_kv(64);                  // prefetch tile 1 (lands during iter 0)

    for (int jt = 0; jt < 16; jt++) {
        const int cur = jt & 1;
        const f16* Kc = cur ? Ka1 : Ka0;
        const f16* Vc = cur ? Vs1 : Vs0;
        __syncthreads();          // buf[cur] writes visible; prior reads of buf[cur^1] done

        // ---- S = Qa·Ka^T : 2x(16) rows x 64 cols, K=128 ----
        f32x4 Sf[2][4];
        #pragma unroll
        for (int ms = 0; ms < 2; ms++)
            #pragma unroll
            for (int js = 0; js < 4; js++) Sf[ms][js] = (f32x4){0.f, 0.f, 0.f, 0.f};
        #pragma unroll
        for (int k = 0; k < 4; k++) {
            f16x8 bb[4];
            #pragma unroll
            for (int js = 0; js < 4; js++) {
                const int row = js * 16 + l16;
                bb[js] = *(const f16x8*)
                    &Kc[(row << 7) + ((((k << 2) + quad) ^ (row & 7)) << 3)];
            }
            #pragma unroll
            for (int ms = 0; ms < 2; ms++)
                #pragma unroll
                for (int js = 0; js < 4; js++)
                    Sf[ms][js] = __builtin_amdgcn_mfma_f32_16x16x32_f16(
                        af[ms][k], bb[js], Sf[ms][js], 0, 0, 0);
        }

        // ---- online softmax (max tree only; sums via MFMA ones) ----
        #pragma unroll
        for (int ms = 0; ms < 2; ms++) {
            #pragma unroll
            for (int r = 0; r < 4; r++) {
                float tm = fmaxf(fmaxf(Sf[ms][0][r], Sf[ms][1][r]),
                                 fmaxf(Sf[ms][2][r], Sf[ms][3][r]));
                tm = fmaxf(tm, __shfl_xor(tm, 1));
                tm = fmaxf(tm, __shfl_xor(tm, 2));
                tm = fmaxf(tm, __shfl_xor(tm, 4));
                tm = fmaxf(tm, __shfl_xor(tm, 8));
                const float mnew  = fmaxf(m_r[ms][r], tm);
                const float alpha = __expf(m_r[ms][r] - mnew);
                m_r[ms][r] = mnew;

                const int row = wave * 32 + ms * 16 + quad * 4 + r;
                const int rx  = row & 7;
                #pragma unroll
                for (int js = 0; js < 4; js++) {
                    const float p = __expf(Sf[ms][js][r] - mnew);
                    const int col = js * 16 + l16;
                    Pt_s[(row << 6) + (((col >> 3) ^ rx) << 3) + (col & 7)] = (f16)p;
                }
                #pragma unroll
                for (int ds = 0; ds < 4; ds++) Of[ms][ds][r] *= alpha;
                Ol[ms][r] *= alpha;
            }
        }
        // Pt rows are wave-private: in-wave LDS ordering, no barrier

        // ---- O += P·V^T (K=64); l += P·1 ----
        #pragma unroll
        for (int ks = 0; ks < 2; ks++) {
            #pragma unroll
            for (int ms = 0; ms < 2; ms++) {
                const int prow = wave * 32 + ms * 16 + l16;
                f16x8 pa = *(const f16x8*)
                    &Pt_s[(prow << 6) + ((((ks << 2) + quad) ^ (prow & 7)) << 3)];
                #pragma unroll
                for (int ds = 0; ds < 4; ds++) {
                    const int vrow = ds * 16 + l16;
                    f16x8 vv = *(const f16x8*)
                        &Vc[(vrow << 6) + ((((ks << 2) + quad) ^ (vrow & 7)) << 3)];
                    Of[ms][ds] = __builtin_amdgcn_mfma_f32_16x16x32_f16(
                        pa, vv, Of[ms][ds], 0, 0, 0);
                }
                Ol[ms] = __builtin_amdgcn_mfma_f32_16x16x32_f16(
                    pa, ones, Ol[ms], 0, 0, 0);
            }
        }

        // ---- pipeline tail: write tile jt+1 to buf[cur^1], prefetch jt+2 ----
        // Safe: buf[cur^1] was last read in iter jt-1, separated by this
        // iteration's barrier. Next read happens after iter jt+1's barrier.
        if (jt < 15) {
            store_kv(cur ? Ka0 : Ka1, cur ? Vs0 : Vs1);
            if (jt < 14) load_kv((jt + 2) * 64);
        }
    }

    // ---- epilogue ----
    #pragma unroll
    for (int ms = 0; ms < 2; ms++) {
        #pragma unroll
        for (int r = 0; r < 4; r++) {
            const float inv = 1.0f / Ol[ms][r];
            const int i = i0 + wave * 32 + ms * 16 + quad * 4 + r;
            #pragma unroll
            for (int ds = 0; ds < 4; ds++) {
                const int d = ds * 16 + l16;
                out[((size_t)(b * Cch + h * Dh + d)) * Nn + i] = Of[ms][ds][r] * inv;
            }
        }
    }
}

// ---------------------------------------------------------------------------
extern "C" void kernel_launch(void* const* d_in, const int* in_sizes, int n_in,
                              void* d_out, int out_size, void* d_ws, size_t ws_size,
                              hipStream_t stream)
{
    const float* x     = (const float*)d_in[0];
    const float* Wq    = (const float*)d_in[1];
    const float* bq    = (const float*)d_in[2];
    const float* Wk    = (const float*)d_in[3];
    const float* bk    = (const float*)d_in[4];
    const float* Wv    = (const float*)d_in[5];
    const float* bv    = (const float*)d_in[6];
    const float* rel_h = (const float*)d_in[7];
    const float* rel_w = (const float*)d_in[8];

    f16* ws = (f16*)d_ws;
    const size_t SZQ = (size_t)Bb * NH * Nn * Dh;    // 4 Mi elems
    f16* qt   = ws;                                  // 8 MB
    f16* kt   = ws + SZQ;                            // 8 MB
    f16* vbuf = ws + 2 * SZQ;                        // 8 MB
    f16* relt = ws + 3 * SZQ;                        // 0.5 MB
    f16* xth  = ws + 3 * SZQ + (size_t)NH * Nn * Dh; // 8 MB  [b][n][c]
    f16* Wh   = xth + SZQ;                           // 0.4 MB [768][256]

    prep_kernel<<<dim3(2816), 256, 0, stream>>>(
        x, Wq, Wk, Wv, rel_h, rel_w, xth, Wh, relt);
    gemm_qkv<<<dim3(Nn / 128, 6, Bb), 256, 0, stream>>>(
        Wh, xth, bq, bk, bv, qt, kt, vbuf);
    attn_mfma<<<dim3(Nn / 128, NH, Bb), 256, 0, stream>>>(
        qt, kt, relt, vbuf, (float*)d_out);
}